// Round 2
// baseline (311.626 us; speedup 1.0000x reference)
//
#include <hip/hip_runtime.h>
#include <math.h>

#define T_TGT 50
#define NCLS 80
#define NBATCH 16

// 512 cells per block (2 per thread). blocks per batch per layer:
#define NB_L0 3     // ceil(3*19*19 / 512)  = ceil(1083/512)
#define NB_L1 9     // ceil(3*38*38 / 512)  = ceil(4332/512)
#define NB_L2 34    // ceil(3*76*76 / 512)  = ceil(17328/512)
#define NB_MAIN ((NB_L0 + NB_L1 + NB_L2) * NBATCH)   // 736
#define NB_TOTAL NB_MAIN                             // class loss fused in

// NOTE (R4 post-mortem, prev session): do NOT use a per-block device-scope
// atomic/fence finish pattern here — single-address device atomics +
// __threadfence (L2 writeback on non-coherent XCD L2s) serialize at ~25ns
// each = +40us at 2k blocks. Two stream-ordered nodes are cheaper.
// R2: grid cut 2040 -> 736 blocks; class blocks deleted (fused into the
// winner-cell epilogue); 2 cells/thread halves per-target LDS traffic.

__constant__ float c_anchors[18] = {10,13,16,30,33,23,30,61,62,45,
                                    59,119,116,90,156,198,373,326};

__device__ __forceinline__ float softplusf(float x){
    return fmaxf(x, 0.f) + log1pf(expf(-fabsf(x)));
}
__device__ __forceinline__ float bcef(float x, float t){
    return t * softplusf(-x) + (1.f - t) * softplusf(x);
}

// SoA shared layout: aligned float4 boxes (ds_read_b128 broadcast) compacted
// to valid targets; winner metadata indexed by ORIGINAL target idx (read only
// in the epilogue); per-cell winner map filled by scatter, not scanned.
struct SmemMain {
    float4 box[T_TGT];   // compacted: valid targets only
    float  thr[T_TGT];   // compacted: 0.7 * truth_area
    float2 fxy[T_TGT];   // by original t
    float2 lwh[T_TGT];
    float  w2[T_TGT];
    int    cls[T_TGT];
    int    win[512];     // per-cell winning target idx, -1 if none
    int    nval;
};

template<int H, int STRIDE, int GROUP>
__device__ float main_cells(const float* __restrict__ raw,
                            const float* __restrict__ targets,
                            int b, int cb, int tid, SmemMain* sm)
{
    constexpr int HH = H * H;
    constexpr int CELLS = 3 * HH;

    // ---- issue the 10 channel loads FIRST so they overlap the target
    //      preprocessing + barriers (compiler won't hoist across s_barrier)
    const int c0 = cb * 512 + tid;
    const int c1 = c0 + 256;
    const bool ok0 = (c0 < CELLS);
    const bool ok1 = (c1 < CELLS);
    int a0 = 0, j0 = 0, i0 = 0, rem0 = 0;
    int a1 = 0, j1 = 0, i1 = 0, rem1 = 0;
    float y00=0.f, y01=0.f, y02=0.f, y03=0.f, y04=0.f;
    float y10=0.f, y11=0.f, y12=0.f, y13=0.f, y14=0.f;
    if (ok0) {
        a0 = c0 / HH; rem0 = c0 - a0 * HH; j0 = rem0 / H; i0 = rem0 - j0 * H;
        const float* base = raw + ((size_t)b * 255 + a0 * 85) * HH + rem0;
        y00 = base[0]; y01 = base[HH]; y02 = base[2*HH];
        y03 = base[3*HH]; y04 = base[4*HH];
    }
    if (ok1) {
        a1 = c1 / HH; rem1 = c1 - a1 * HH; j1 = rem1 / H; i1 = rem1 - j1 * H;
        const float* base = raw + ((size_t)b * 255 + a1 * 85) * HH + rem1;
        y10 = base[0]; y11 = base[HH]; y12 = base[2*HH];
        y13 = base[3*HH]; y14 = base[4*HH];
    }

    sm->win[tid] = -1;
    sm->win[tid + 256] = -1;

    // ---- per-target metadata + valid-compaction (wave 0 only)
    bool scat = false; int rel = 0;
    if (tid < 64) {
        bool valid = false;
        float tx = 0.f, ty = 0.f, tw = 0.f, th = 0.f, tarea = 0.f;
        int bestn = 0;
        if (tid < T_TGT) {
            const float* lab = targets + ((size_t)b * T_TGT + tid) * 5;
            float cf = lab[0], x = lab[1], y = lab[2], w = lab[3], h = lab[4];
            valid = (cf + x + y + w + h) > 0.f;
            const float fs = (float)H;
            tx = x * fs; ty = y * fs; tw = w * fs; th = h * fs;
            tarea = tw * th;
            float best = -1.f;
            #pragma unroll
            for (int n = 0; n < 9; n++) {
                float aw = c_anchors[2*n]   * (1.f / STRIDE);
                float ah = c_anchors[2*n+1] * (1.f / STRIDE);
                float mw = fminf(tw, aw), mh = fminf(th, ah);
                float inter = (mw > 0.f && mh > 0.f) ? mw * mh : 0.f;
                float iou = inter / (tarea + aw * ah - inter);
                if (iou > best) { best = iou; bestn = n; }
            }
            sm->cls[tid] = (int)cf;
        }
        const unsigned long long vm = __ballot(valid);
        if (valid) {
            // compacted slot for the ignore loop (order irrelevant: OR-reduce)
            const int idx = __popcll(vm & ((1ull << tid) - 1ull));
            sm->box[idx] = make_float4(tx - tw*0.5f, ty - th*0.5f,
                                       tx + tw*0.5f, ty + th*0.5f);
            sm->thr[idx] = 0.7f * tarea;
            // winner metadata by original index
            const int gi = (int)tx, gj = (int)ty;
            sm->fxy[tid] = make_float2(tx - (float)gi, ty - (float)gj);
            const int bn = bestn % 3;
            const float awm = c_anchors[2*(3*GROUP + bn)]   * (1.f / STRIDE);
            const float ahm = c_anchors[2*(3*GROUP + bn)+1] * (1.f / STRIDE);
            sm->lwh[tid] = make_float2(logf(tw / awm + 1e-16f),
                                       logf(th / ahm + 1e-16f));
            sm->w2[tid] = 2.f - tarea / ((float)H * (float)H);
            // winner scatter target (drop semantics: OOB grid idx dropped)
            if (((bestn / 3) == GROUP) &&
                ((unsigned)gi < (unsigned)H) && ((unsigned)gj < (unsigned)H)) {
                const int ct = bn * HH + gj * H + gi;
                rel = ct - cb * 512;
                scat = (rel >= 0) && (rel < 512);
            }
        }
        if (tid == 0) sm->nval = __popcll(vm);
    }
    __syncthreads();                          // win[] init + meta visible
    if (scat) atomicMax(&sm->win[rel], tid);  // last-target-wins == max(t)
    __syncthreads();

    const int w0 = sm->win[tid];
    const int w1 = sm->win[tid + 256];
    const int nval = sm->nval;                // E[nval] ~ 25.5 (vs fixed 50)

    // pred boxes (zeros for dead lanes are NaN-free)
    float atlx0=0.f, atly0=0.f, abrx0=0.f, abry0=0.f, ca0=0.f;
    float atlx1=0.f, atly1=0.f, abrx1=0.f, abry1=0.f, ca1=0.f;
    if (ok0) {
        const float s0 = 1.f / (1.f + expf(-y00));
        const float s1 = 1.f / (1.f + expf(-y01));
        const float mw = c_anchors[2*(3*GROUP + a0)]   * (1.f / STRIDE);
        const float mh = c_anchors[2*(3*GROUP + a0)+1] * (1.f / STRIDE);
        const float px = s0 + (float)i0, py = s1 + (float)j0;
        const float pw = expf(y02) * mw, ph = expf(y03) * mh;
        atlx0 = px - pw*0.5f; atly0 = py - ph*0.5f;
        abrx0 = px + pw*0.5f; abry0 = py + ph*0.5f;
        ca0 = 0.7f * (pw * ph);
    }
    if (ok1) {
        const float s0 = 1.f / (1.f + expf(-y10));
        const float s1 = 1.f / (1.f + expf(-y11));
        const float mw = c_anchors[2*(3*GROUP + a1)]   * (1.f / STRIDE);
        const float mh = c_anchors[2*(3*GROUP + a1)+1] * (1.f / STRIDE);
        const float px = s0 + (float)i1, py = s1 + (float)j1;
        const float pw = expf(y12) * mw, ph = expf(y13) * mh;
        atlx1 = px - pw*0.5f; atly1 = py - ph*0.5f;
        abrx1 = px + pw*0.5f; abry1 = py + ph*0.5f;
        ca1 = 0.7f * (pw * ph);
    }

    // winner/dead lanes pre-set ign so the wave-uniform early-exit fires.
    bool ign0 = (!ok0) || (w0 >= 0);
    bool ign1 = (!ok1) || (w1 >= 0);

    // piou > 0.7  <=>  1.7*ai - 0.7*area_a > 0.7*area_b  (given overlap > 0)
    // one box/thr broadcast feeds BOTH cells
    #define IGN_BODY(tt) {                                          \
        const float4 bx = sm->box[tt];                              \
        const float thr = sm->thr[tt];                              \
        float tlx = fmaxf(atlx0, bx.x);                             \
        float tly = fmaxf(atly0, bx.y);                             \
        float brx = fminf(abrx0, bx.z);                             \
        float bry = fminf(abry0, bx.w);                             \
        float dx = brx - tlx, dy = bry - tly;                       \
        ign0 = ign0 || ((fminf(dx, dy) > 0.f) &&                    \
                        (fmaf(1.7f, dx * dy, -ca0) > thr));         \
        tlx = fmaxf(atlx1, bx.x);                                   \
        tly = fmaxf(atly1, bx.y);                                   \
        brx = fminf(abrx1, bx.z);                                   \
        bry = fminf(abry1, bx.w);                                   \
        dx = brx - tlx; dy = bry - tly;                             \
        ign1 = ign1 || ((fminf(dx, dy) > 0.f) &&                    \
                        (fmaf(1.7f, dx * dy, -ca1) > thr)); }

    int t = 0;
    bool done = __all(ign0 && ign1);
    while (!done && t + 4 <= nval) {
        IGN_BODY(t) IGN_BODY(t+1) IGN_BODY(t+2) IGN_BODY(t+3)
        t += 4;
        done = __all(ign0 && ign1);
    }
    if (!done)
        for (; t < nval; ++t) IGN_BODY(t)
    #undef IGN_BODY

    float local = 0.f;

    // epilogue per cell; winner path includes the FUSED class loss
    #define EPILOGUE(w, ign, x0, x1, x2, x3, x4, aa, rr) {              \
        if (w >= 0) {                                                   \
            local += softplusf(-(x4));                                  \
            const float w2v = sm->w2[w];                                \
            const float2 f = sm->fxy[w];                                \
            local += w2v * (bcef(x0, f.x) + bcef(x1, f.y));             \
            const float2 lw = sm->lwh[w];                               \
            const float dw = (x2) - lw.x, dh = (x3) - lw.y;             \
            local += 0.5f * w2v * (dw * dw + dh * dh);                  \
            const int cls = sm->cls[w];                                 \
            const float* cb_ = raw + ((size_t)b*255 + (aa)*85 + 5)*HH + (rr); \
            float cl = 0.f;                                             \
            _Pragma("unroll 20")                                        \
            for (int cc = 0; cc < NCLS; cc++)                           \
                cl += softplusf(cb_[(size_t)cc * HH]);                  \
            local += cl - cb_[(size_t)cls * HH];                        \
        } else if (!(ign)) {                                            \
            local += softplusf(x4);                                     \
        } }

    EPILOGUE(w0, ign0, y00, y01, y02, y03, y04, a0, rem0)
    EPILOGUE(w1, ign1, y10, y11, y12, y13, y14, a1, rem1)
    #undef EPILOGUE

    return local;
}

__global__ __launch_bounds__(256)
void yolo_fused(const float* __restrict__ r0,
                const float* __restrict__ r1,
                const float* __restrict__ r2,
                const float* __restrict__ targets,
                float* __restrict__ partial)
{
    __shared__ SmemMain sm;
    __shared__ float s_wsum[4];

    const int blk = blockIdx.x;
    const int tid = threadIdx.x;
    float local = 0.f;

    if (blk < NB_L0 * NBATCH) {
        int b = blk / NB_L0, cb = blk - b * NB_L0;
        local = main_cells<19, 32, 2>(r0, targets, b, cb, tid, &sm);
    } else if (blk < (NB_L0 + NB_L1) * NBATCH) {
        int q = blk - NB_L0 * NBATCH;
        int b = q / NB_L1, cb = q - b * NB_L1;
        local = main_cells<38, 16, 1>(r1, targets, b, cb, tid, &sm);
    } else {
        int q = blk - (NB_L0 + NB_L1) * NBATCH;
        int b = q / NB_L2, cb = q - b * NB_L2;
        local = main_cells<76, 8, 0>(r2, targets, b, cb, tid, &sm);
    }

    // block reduction -> unique partial slot (no global atomics)
    for (int off = 32; off > 0; off >>= 1)
        local += __shfl_down(local, off, 64);
    const int lane = tid & 63, wv = tid >> 6;
    if (lane == 0) s_wsum[wv] = local;
    __syncthreads();
    if (tid == 0)
        partial[blk] = s_wsum[0] + s_wsum[1] + s_wsum[2] + s_wsum[3];
}

__global__ __launch_bounds__(256)
void yolo_reduce(const float4* __restrict__ partial4, float* __restrict__ out)
{
    const int tid = threadIdx.x;
    constexpr int NV = NB_TOTAL / 4;    // 184 float4s (NB_TOTAL % 4 == 0)
    float s = 0.f;
    if (tid < NV) {
        float4 v = partial4[tid];
        s = v.x + v.y + v.z + v.w;
    }
    for (int off = 32; off > 0; off >>= 1)
        s += __shfl_down(s, off, 64);
    __shared__ float w[4];
    if ((tid & 63) == 0) w[tid >> 6] = s;
    __syncthreads();
    if (tid == 0) out[0] = w[0] + w[1] + w[2] + w[3];
}

extern "C" void kernel_launch(void* const* d_in, const int* in_sizes, int n_in,
                              void* d_out, int out_size, void* d_ws, size_t ws_size,
                              hipStream_t stream)
{
    const float* out0 = (const float*)d_in[0];
    const float* out1 = (const float*)d_in[1];
    const float* out2 = (const float*)d_in[2];
    const float* tgt  = (const float*)d_in[3];
    float* out = (float*)d_out;
    float* partial = (float*)d_ws;   // NB_TOTAL floats, all slots written

    yolo_fused<<<NB_TOTAL, 256, 0, stream>>>(out0, out1, out2, tgt, partial);
    yolo_reduce<<<1, 256, 0, stream>>>((const float4*)partial, out);
}

// Round 3
// 158.215 us; speedup vs baseline: 1.9696x; 1.9696x over previous
//
#include <hip/hip_runtime.h>
#include <math.h>

#define T_TGT 50
#define NCLS 80
#define NBATCH 16

// 512 cells per block (2 per thread). blocks per batch per layer:
#define NB_L0 3     // ceil(3*19*19 / 512)  = ceil(1083/512)
#define NB_L1 9     // ceil(3*38*38 / 512)  = ceil(4332/512)
#define NB_L2 34    // ceil(3*76*76 / 512)  = ceil(17328/512)
#define NB_MAIN ((NB_L0 + NB_L1 + NB_L2) * NBATCH)   // 736
#define NB_TOTAL NB_MAIN                             // class loss fused in

// NOTE (R4 post-mortem, prev session): do NOT use a per-block device-scope
// atomic/fence finish pattern — single-address device atomics + threadfence
// serialize at ~25ns each. Two stream-ordered nodes are cheaper.
// R2 post-mortem: fusing class loss as a PER-THREAD 80-load serial walk in a
// divergent branch was a 4x regression (198us/dispatch, VGPR=32 -> no load
// pipelining, ~80 dependent HBM round trips per winner thread). R3: winner
// cells go into an LDS queue; waves drain it with LANE-PARALLEL class loads
// (one load instruction covers 64 classes -> latency paid once).

__constant__ float c_anchors[18] = {10,13,16,30,33,23,30,61,62,45,
                                    59,119,116,90,156,198,373,326};

__device__ __forceinline__ float softplusf(float x){
    return fmaxf(x, 0.f) + log1pf(expf(-fabsf(x)));
}
__device__ __forceinline__ float bcef(float x, float t){
    return t * softplusf(-x) + (1.f - t) * softplusf(x);
}

// SoA shared layout: aligned float4 boxes (ds_read_b128 broadcast) compacted
// to valid targets; winner metadata indexed by ORIGINAL target idx (read only
// in the epilogue); per-cell winner map filled by scatter, not scanned.
struct SmemMain {
    float4 box[T_TGT];   // compacted: valid targets only
    float  thr[T_TGT];   // compacted: 0.7 * truth_area
    float2 fxy[T_TGT];   // by original t
    float2 lwh[T_TGT];
    float  w2[T_TGT];
    int    cls[T_TGT];
    int    win[512];     // per-cell winning target idx, -1 if none
    int    nval;
    int    qn;           // winner-cell queue for lane-parallel class loss
    int    qcell[T_TGT]; // (a << 16) | rem
    int    qcls[T_TGT];
};

template<int H, int STRIDE, int GROUP>
__device__ float main_cells(const float* __restrict__ raw,
                            const float* __restrict__ targets,
                            int b, int cb, int tid, SmemMain* sm)
{
    constexpr int HH = H * H;
    constexpr int CELLS = 3 * HH;

    // ---- issue the 10 channel loads FIRST so they overlap the target
    //      preprocessing + barriers (compiler won't hoist across s_barrier)
    const int c0 = cb * 512 + tid;
    const int c1 = c0 + 256;
    const bool ok0 = (c0 < CELLS);
    const bool ok1 = (c1 < CELLS);
    int a0 = 0, j0 = 0, i0 = 0, rem0 = 0;
    int a1 = 0, j1 = 0, i1 = 0, rem1 = 0;
    float y00=0.f, y01=0.f, y02=0.f, y03=0.f, y04=0.f;
    float y10=0.f, y11=0.f, y12=0.f, y13=0.f, y14=0.f;
    if (ok0) {
        a0 = c0 / HH; rem0 = c0 - a0 * HH; j0 = rem0 / H; i0 = rem0 - j0 * H;
        const float* base = raw + ((size_t)b * 255 + a0 * 85) * HH + rem0;
        y00 = base[0]; y01 = base[HH]; y02 = base[2*HH];
        y03 = base[3*HH]; y04 = base[4*HH];
    }
    if (ok1) {
        a1 = c1 / HH; rem1 = c1 - a1 * HH; j1 = rem1 / H; i1 = rem1 - j1 * H;
        const float* base = raw + ((size_t)b * 255 + a1 * 85) * HH + rem1;
        y10 = base[0]; y11 = base[HH]; y12 = base[2*HH];
        y13 = base[3*HH]; y14 = base[4*HH];
    }

    sm->win[tid] = -1;
    sm->win[tid + 256] = -1;
    if (tid == 0) sm->qn = 0;

    // ---- per-target metadata + valid-compaction (wave 0 only)
    bool scat = false; int rel = 0;
    if (tid < 64) {
        bool valid = false;
        float tx = 0.f, ty = 0.f, tw = 0.f, th = 0.f, tarea = 0.f;
        int bestn = 0;
        if (tid < T_TGT) {
            const float* lab = targets + ((size_t)b * T_TGT + tid) * 5;
            float cf = lab[0], x = lab[1], y = lab[2], w = lab[3], h = lab[4];
            valid = (cf + x + y + w + h) > 0.f;
            const float fs = (float)H;
            tx = x * fs; ty = y * fs; tw = w * fs; th = h * fs;
            tarea = tw * th;
            float best = -1.f;
            #pragma unroll
            for (int n = 0; n < 9; n++) {
                float aw = c_anchors[2*n]   * (1.f / STRIDE);
                float ah = c_anchors[2*n+1] * (1.f / STRIDE);
                float mw = fminf(tw, aw), mh = fminf(th, ah);
                float inter = (mw > 0.f && mh > 0.f) ? mw * mh : 0.f;
                float iou = inter / (tarea + aw * ah - inter);
                if (iou > best) { best = iou; bestn = n; }
            }
            sm->cls[tid] = (int)cf;
        }
        const unsigned long long vm = __ballot(valid);
        if (valid) {
            // compacted slot for the ignore loop (order irrelevant: OR-reduce)
            const int idx = __popcll(vm & ((1ull << tid) - 1ull));
            sm->box[idx] = make_float4(tx - tw*0.5f, ty - th*0.5f,
                                       tx + tw*0.5f, ty + th*0.5f);
            sm->thr[idx] = 0.7f * tarea;
            // winner metadata by original index
            const int gi = (int)tx, gj = (int)ty;
            sm->fxy[tid] = make_float2(tx - (float)gi, ty - (float)gj);
            const int bn = bestn % 3;
            const float awm = c_anchors[2*(3*GROUP + bn)]   * (1.f / STRIDE);
            const float ahm = c_anchors[2*(3*GROUP + bn)+1] * (1.f / STRIDE);
            sm->lwh[tid] = make_float2(logf(tw / awm + 1e-16f),
                                       logf(th / ahm + 1e-16f));
            sm->w2[tid] = 2.f - tarea / ((float)H * (float)H);
            // winner scatter target (drop semantics: OOB grid idx dropped)
            if (((bestn / 3) == GROUP) &&
                ((unsigned)gi < (unsigned)H) && ((unsigned)gj < (unsigned)H)) {
                const int ct = bn * HH + gj * H + gi;
                rel = ct - cb * 512;
                scat = (rel >= 0) && (rel < 512);
            }
        }
        if (tid == 0) sm->nval = __popcll(vm);
    }
    __syncthreads();                          // win[]/qn init + meta visible
    if (scat) atomicMax(&sm->win[rel], tid);  // last-target-wins == max(t)
    __syncthreads();

    const int w0 = sm->win[tid];
    const int w1 = sm->win[tid + 256];
    const int nval = sm->nval;                // E[nval] ~ 25.5 (vs fixed 50)

    // pred boxes (zeros for dead lanes are NaN-free)
    float atlx0=0.f, atly0=0.f, abrx0=0.f, abry0=0.f, ca0=0.f;
    float atlx1=0.f, atly1=0.f, abrx1=0.f, abry1=0.f, ca1=0.f;
    if (ok0) {
        const float s0 = 1.f / (1.f + expf(-y00));
        const float s1 = 1.f / (1.f + expf(-y01));
        const float mw = c_anchors[2*(3*GROUP + a0)]   * (1.f / STRIDE);
        const float mh = c_anchors[2*(3*GROUP + a0)+1] * (1.f / STRIDE);
        const float px = s0 + (float)i0, py = s1 + (float)j0;
        const float pw = expf(y02) * mw, ph = expf(y03) * mh;
        atlx0 = px - pw*0.5f; atly0 = py - ph*0.5f;
        abrx0 = px + pw*0.5f; abry0 = py + ph*0.5f;
        ca0 = 0.7f * (pw * ph);
    }
    if (ok1) {
        const float s0 = 1.f / (1.f + expf(-y10));
        const float s1 = 1.f / (1.f + expf(-y11));
        const float mw = c_anchors[2*(3*GROUP + a1)]   * (1.f / STRIDE);
        const float mh = c_anchors[2*(3*GROUP + a1)+1] * (1.f / STRIDE);
        const float px = s0 + (float)i1, py = s1 + (float)j1;
        const float pw = expf(y12) * mw, ph = expf(y13) * mh;
        atlx1 = px - pw*0.5f; atly1 = py - ph*0.5f;
        abrx1 = px + pw*0.5f; abry1 = py + ph*0.5f;
        ca1 = 0.7f * (pw * ph);
    }

    // winner/dead lanes pre-set ign so the wave-uniform early-exit fires.
    bool ign0 = (!ok0) || (w0 >= 0);
    bool ign1 = (!ok1) || (w1 >= 0);

    // piou > 0.7  <=>  1.7*ai - 0.7*area_a > 0.7*area_b  (given overlap > 0)
    // one box/thr broadcast feeds BOTH cells
    #define IGN_BODY(tt) {                                          \
        const float4 bx = sm->box[tt];                              \
        const float thr = sm->thr[tt];                              \
        float tlx = fmaxf(atlx0, bx.x);                             \
        float tly = fmaxf(atly0, bx.y);                             \
        float brx = fminf(abrx0, bx.z);                             \
        float bry = fminf(abry0, bx.w);                             \
        float dx = brx - tlx, dy = bry - tly;                       \
        ign0 = ign0 || ((fminf(dx, dy) > 0.f) &&                    \
                        (fmaf(1.7f, dx * dy, -ca0) > thr));         \
        tlx = fmaxf(atlx1, bx.x);                                   \
        tly = fmaxf(atly1, bx.y);                                   \
        brx = fminf(abrx1, bx.z);                                   \
        bry = fminf(abry1, bx.w);                                   \
        dx = brx - tlx; dy = bry - tly;                             \
        ign1 = ign1 || ((fminf(dx, dy) > 0.f) &&                    \
                        (fmaf(1.7f, dx * dy, -ca1) > thr)); }

    int t = 0;
    bool done = __all(ign0 && ign1);
    while (!done && t + 4 <= nval) {
        IGN_BODY(t) IGN_BODY(t+1) IGN_BODY(t+2) IGN_BODY(t+3)
        t += 4;
        done = __all(ign0 && ign1);
    }
    if (!done)
        for (; t < nval; ++t) IGN_BODY(t)
    #undef IGN_BODY

    float local = 0.f;

    // per-cell epilogue: xy/wh/obj losses per-thread (cheap); winner cells
    // are queued for lane-parallel class handling after the barrier.
    #define EPILOGUE(w, ign, x0, x1, x2, x3, x4, aa, rr) {              \
        if (w >= 0) {                                                   \
            local += softplusf(-(x4));                                  \
            const float w2v = sm->w2[w];                                \
            const float2 f = sm->fxy[w];                                \
            local += w2v * (bcef(x0, f.x) + bcef(x1, f.y));             \
            const float2 lw = sm->lwh[w];                               \
            const float dw = (x2) - lw.x, dh = (x3) - lw.y;             \
            local += 0.5f * w2v * (dw * dw + dh * dh);                  \
            const int q = atomicAdd(&sm->qn, 1);                        \
            sm->qcell[q] = ((aa) << 16) | (rr);                         \
            sm->qcls[q]  = sm->cls[w];                                  \
        } else if (!(ign)) {                                            \
            local += softplusf(x4);                                     \
        } }

    EPILOGUE(w0, ign0, y00, y01, y02, y03, y04, a0, rem0)
    EPILOGUE(w1, ign1, y10, y11, y12, y13, y14, a1, rem1)
    #undef EPILOGUE

    __syncthreads();                       // queue visible to all waves
    const int nq = sm->qn;
    const int lane = tid & 63, wv = tid >> 6;
    for (int q = wv; q < nq; q += 4) {     // one wave per winner cell
        const int cell = sm->qcell[q];
        const int cls  = sm->qcls[q];
        const int aa = cell >> 16, rr = cell & 0xFFFF;
        const float* base = raw + ((size_t)b * 255 + aa * 85 + 5) * HH + rr;
        // class loss = sum_c softplus(x_c) - x_cls   (lane-parallel gather)
        float xc = base[(size_t)lane * HH];                 // classes 0..63
        local += softplusf(xc) - ((lane == cls) ? xc : 0.f);
        if (lane < 16) {
            float xh = base[(size_t)(64 + lane) * HH];      // classes 64..79
            local += softplusf(xh) - ((lane + 64 == cls) ? xh : 0.f);
        }
    }
    return local;
}

__global__ __launch_bounds__(256)
void yolo_fused(const float* __restrict__ r0,
                const float* __restrict__ r1,
                const float* __restrict__ r2,
                const float* __restrict__ targets,
                float* __restrict__ partial)
{
    __shared__ SmemMain sm;
    __shared__ float s_wsum[4];

    const int blk = blockIdx.x;
    const int tid = threadIdx.x;
    float local = 0.f;

    if (blk < NB_L0 * NBATCH) {
        int b = blk / NB_L0, cb = blk - b * NB_L0;
        local = main_cells<19, 32, 2>(r0, targets, b, cb, tid, &sm);
    } else if (blk < (NB_L0 + NB_L1) * NBATCH) {
        int q = blk - NB_L0 * NBATCH;
        int b = q / NB_L1, cb = q - b * NB_L1;
        local = main_cells<38, 16, 1>(r1, targets, b, cb, tid, &sm);
    } else {
        int q = blk - (NB_L0 + NB_L1) * NBATCH;
        int b = q / NB_L2, cb = q - b * NB_L2;
        local = main_cells<76, 8, 0>(r2, targets, b, cb, tid, &sm);
    }

    // block reduction -> unique partial slot (no global atomics)
    for (int off = 32; off > 0; off >>= 1)
        local += __shfl_down(local, off, 64);
    const int lane = tid & 63, wv = tid >> 6;
    if (lane == 0) s_wsum[wv] = local;
    __syncthreads();
    if (tid == 0)
        partial[blk] = s_wsum[0] + s_wsum[1] + s_wsum[2] + s_wsum[3];
}

__global__ __launch_bounds__(256)
void yolo_reduce(const float4* __restrict__ partial4, float* __restrict__ out)
{
    const int tid = threadIdx.x;
    constexpr int NV = NB_TOTAL / 4;    // 184 float4s (NB_TOTAL % 4 == 0)
    float s = 0.f;
    if (tid < NV) {
        float4 v = partial4[tid];
        s = v.x + v.y + v.z + v.w;
    }
    for (int off = 32; off > 0; off >>= 1)
        s += __shfl_down(s, off, 64);
    __shared__ float w[4];
    if ((tid & 63) == 0) w[tid >> 6] = s;
    __syncthreads();
    if (tid == 0) out[0] = w[0] + w[1] + w[2] + w[3];
}

extern "C" void kernel_launch(void* const* d_in, const int* in_sizes, int n_in,
                              void* d_out, int out_size, void* d_ws, size_t ws_size,
                              hipStream_t stream)
{
    const float* out0 = (const float*)d_in[0];
    const float* out1 = (const float*)d_in[1];
    const float* out2 = (const float*)d_in[2];
    const float* tgt  = (const float*)d_in[3];
    float* out = (float*)d_out;
    float* partial = (float*)d_ws;   // NB_TOTAL floats, all slots written

    yolo_fused<<<NB_TOTAL, 256, 0, stream>>>(out0, out1, out2, tgt, partial);
    yolo_reduce<<<1, 256, 0, stream>>>((const float4*)partial, out);
}

// Round 5
// 149.199 us; speedup vs baseline: 2.0887x; 1.0604x over previous
//
#include <hip/hip_runtime.h>
#include <math.h>

#define T_TGT 50
#define NCLS 80
#define NBATCH 16

// blocks per batch per layer: ceil(3*H*H / 256)
#define NB_L0 5     // 3*19*19 = 1083
#define NB_L1 17    // 3*38*38 = 4332
#define NB_L2 68    // 3*76*76 = 17328
#define NB_MAIN ((NB_L0 + NB_L1 + NB_L2) * NBATCH)   // 1440
#define N_CLS_UNITS (T_TGT * NBATCH * 3)             // 2400
#define NB_CLS ((N_CLS_UNITS + 3) / 4)               // 600 (4 waves/block)
#define NB_TOTAL (NB_MAIN + NB_CLS)                  // 2040

// NOTE (prev session): no per-block device-scope atomic/fence finish pattern
// (2040 single-address atomics + threadfence = +40us). Two nodes are cheaper.
// R2 post-mortem: per-thread serial 80-load class walk in a divergent branch
// = 4x regression (dependent HBM round trips, no pipelining). Class loss must
// stay LANE-PARALLEL.
// R3 post-mortem: fusing class gathers into main blocks' critical path +
// 2 cells/thread = +10us vs R1. Concurrent separate blocks hide the gather
// latency for free. KEEP the R1 structure.
// R4: class blocks FIRST in dispatch order so their cold-HBM gathers overlap
// main-block compute instead of forming the straggler tail.
// (R4 bench was an infra failure — container died twice; resubmitting as-is.)

__constant__ float c_anchors[18] = {10,13,16,30,33,23,30,61,62,45,
                                    59,119,116,90,156,198,373,326};

__device__ __forceinline__ float softplusf(float x){
    return fmaxf(x, 0.f) + log1pf(expf(-fabsf(x)));
}
__device__ __forceinline__ float bcef(float x, float t){
    return t * softplusf(-x) + (1.f - t) * softplusf(x);
}

// SoA shared layout: aligned float4 boxes (ds_read_b128 broadcast) compacted
// to valid targets; winner metadata indexed by ORIGINAL target idx (read only
// in the epilogue); per-cell winner map filled by scatter, not scanned.
struct SmemMain {
    float4 box[T_TGT];   // compacted: valid targets only
    float  thr[T_TGT];   // compacted: 0.7 * truth_area
    float  fx[T_TGT];    // by original t
    float  fy[T_TGT];
    float  lw[T_TGT];
    float  lh[T_TGT];
    float  w2[T_TGT];
    int    win[256];     // per-cell winning target idx, -1 if none
    int    nval;
};

template<int H, int STRIDE, int GROUP>
__device__ float main_cells(const float* __restrict__ raw,
                            const float* __restrict__ targets,
                            int b, int cb, int tid, SmemMain* sm)
{
    constexpr int HH = H * H;
    constexpr int CELLS = 3 * HH;

    // ---- issue the 5 channel loads FIRST so they overlap the target
    //      preprocessing + barriers (compiler won't hoist across s_barrier)
    const int c = cb * 256 + tid;
    const bool cell_ok = (c < CELLS);
    int a = 0, j = 0, i = 0;
    float x0 = 0.f, x1 = 0.f, x2 = 0.f, x3 = 0.f, x4 = 0.f;
    if (cell_ok) {
        a = c / HH;
        const int rem = c - a * HH;
        j = rem / H;
        i = rem - j * H;
        const float* base = raw + ((size_t)b * 255 + a * 85) * HH + rem;
        x0 = base[0];
        x1 = base[HH];
        x2 = base[2 * HH];
        x3 = base[3 * HH];
        x4 = base[4 * HH];
    }

    sm->win[tid] = -1;

    // ---- per-target metadata + valid-compaction (wave 0 only)
    bool scat = false; int rel = 0;
    if (tid < 64) {
        bool valid = false;
        float tx = 0.f, ty = 0.f, tw = 0.f, th = 0.f, tarea = 0.f;
        int bestn = 0;
        if (tid < T_TGT) {
            const float* lab = targets + ((size_t)b * T_TGT + tid) * 5;
            float cf = lab[0], x = lab[1], y = lab[2], w = lab[3], h = lab[4];
            valid = (cf + x + y + w + h) > 0.f;
            const float fs = (float)H;
            tx = x * fs; ty = y * fs; tw = w * fs; th = h * fs;
            tarea = tw * th;
            float best = -1.f;
            #pragma unroll
            for (int n = 0; n < 9; n++) {
                float aw = c_anchors[2*n]   * (1.f / STRIDE);
                float ah = c_anchors[2*n+1] * (1.f / STRIDE);
                float mw = fminf(tw, aw), mh = fminf(th, ah);
                float inter = (mw > 0.f && mh > 0.f) ? mw * mh : 0.f;
                float iou = inter / (tarea + aw * ah - inter);
                if (iou > best) { best = iou; bestn = n; }
            }
        }
        const unsigned long long vm = __ballot(valid);
        if (valid) {
            // compacted slot for the ignore loop (order irrelevant: OR-reduce)
            const int idx = __popcll(vm & ((1ull << tid) - 1ull));
            sm->box[idx] = make_float4(tx - tw*0.5f, ty - th*0.5f,
                                       tx + tw*0.5f, ty + th*0.5f);
            sm->thr[idx] = 0.7f * tarea;
            // winner metadata by original index
            const int gi = (int)tx, gj = (int)ty;
            sm->fx[tid] = tx - (float)gi;
            sm->fy[tid] = ty - (float)gj;
            const int bn = bestn % 3;
            const float awm = c_anchors[2*(3*GROUP + bn)]   * (1.f / STRIDE);
            const float ahm = c_anchors[2*(3*GROUP + bn)+1] * (1.f / STRIDE);
            sm->lw[tid] = logf(tw / awm + 1e-16f);
            sm->lh[tid] = logf(th / ahm + 1e-16f);
            sm->w2[tid] = 2.f - tarea / ((float)H * (float)H);
            // winner scatter target (drop semantics: OOB grid idx dropped)
            if (((bestn / 3) == GROUP) &&
                ((unsigned)gi < (unsigned)H) && ((unsigned)gj < (unsigned)H)) {
                const int ct = bn * HH + gj * H + gi;
                rel = ct - cb * 256;
                scat = (rel >= 0) && (rel < 256);
            }
        }
        if (tid == 0) sm->nval = __popcll(vm);
    }
    __syncthreads();                       // win[] init + meta visible
    if (scat) atomicMax(&sm->win[rel], tid);  // last-target-wins == max(t)
    __syncthreads();

    float local = 0.f;
    const int winner = sm->win[tid];       // -1 for all non-scattered cells

    // pred box (only meaningful for cell_ok lanes; zeros are NaN-free)
    float atlx = 0.f, atly = 0.f, abrx = 0.f, abry = 0.f, carea_a = 0.f;
    if (cell_ok) {
        const float s0 = 1.f / (1.f + expf(-x0));
        const float s1 = 1.f / (1.f + expf(-x1));
        const float manw = c_anchors[2*(3*GROUP + a)]   * (1.f / STRIDE);
        const float manh = c_anchors[2*(3*GROUP + a)+1] * (1.f / STRIDE);
        const float px = s0 + (float)i, py = s1 + (float)j;
        const float pw = expf(x2) * manw, ph = expf(x3) * manh;
        atlx = px - pw * 0.5f; atly = py - ph * 0.5f;
        abrx = px + pw * 0.5f; abry = py + ph * 0.5f;
        carea_a = 0.7f * (pw * ph);
    }

    // winner lanes never take the noobj branch; dead lanes contribute nothing:
    // pre-set ign so the wave-uniform early-exit can fire sooner.
    bool ign = (!cell_ok) || (winner >= 0);
    const int nval = sm->nval;             // E[nval] ~ 25.5 (vs fixed 50)

    // piou > 0.7  <=>  1.7*ai - 0.7*area_a > 0.7*area_b  (given overlap > 0)
    #define IGN_BODY(tt) {                                          \
        const float4 bx = sm->box[tt];                              \
        const float thr = sm->thr[tt];                              \
        const float tlx = fmaxf(atlx, bx.x);                        \
        const float tly = fmaxf(atly, bx.y);                        \
        const float brx = fminf(abrx, bx.z);                        \
        const float bry = fminf(abry, bx.w);                        \
        const float dx = brx - tlx, dy = bry - tly;                 \
        ign = ign || ((fminf(dx, dy) > 0.f) &&                      \
                      (fmaf(1.7f, dx * dy, -carea_a) > thr)); }

    int t = 0;
    while (t + 4 <= nval) {
        if (__all(ign)) break;             // wave-uniform: cheap scalar check
        IGN_BODY(t) IGN_BODY(t+1) IGN_BODY(t+2) IGN_BODY(t+3)
        t += 4;
    }
    if (!__all(ign))
        for (; t < nval; ++t) IGN_BODY(t)
    #undef IGN_BODY

    if (winner >= 0) {
        local += softplusf(-x4);                     // objectness target = 1
        const float w2v = sm->w2[winner];
        local += w2v * (bcef(x0, sm->fx[winner]) + bcef(x1, sm->fy[winner]));
        const float dw = x2 - sm->lw[winner];
        const float dh = x3 - sm->lh[winner];
        local += 0.5f * w2v * (dw * dw + dh * dh);
    } else if (!ign) {                               // implies cell_ok
        local += softplusf(x4);                      // objectness target = 0
    }
    return local;
}

// class loss for one (target, batch, layer) unit, handled by one wave
__device__ float class_unit(const float* __restrict__ r0,
                            const float* __restrict__ r1,
                            const float* __restrict__ r2,
                            const float* __restrict__ targets,
                            int u, int lane)
{
    const int L   = u / (T_TGT * NBATCH);
    const int rem = u - L * (T_TGT * NBATCH);
    const int b   = rem / T_TGT;
    const int t0  = rem - b * T_TGT;

    const int Hs[3] = {19, 38, 76};
    const float inv_s[3] = {1.f/32.f, 1.f/16.f, 1.f/8.f};
    const int Gs[3] = {2, 1, 0};
    const float* raw = (L == 0) ? r0 : (L == 1) ? r1 : r2;
    const int H = Hs[L];
    const int HH = H * H;
    const float is = inv_s[L];
    const int group = Gs[L];

    int selkey = 0x40000000 | lane;   // sentinel, never matches a real key
    int clsid = 0;
    if (lane < T_TGT) {
        const float* lab = targets + ((size_t)b * T_TGT + lane) * 5;
        float cf = lab[0], x = lab[1], y = lab[2], w = lab[3], h = lab[4];
        bool valid = (cf + x + y + w + h) > 0.f;
        float fs = (float)H;
        float tx = x * fs, ty = y * fs, tw = w * fs, th = h * fs;
        float tarea = tw * th;
        float best = -1.f; int bestn = 0;
        #pragma unroll
        for (int n = 0; n < 9; n++) {
            float aw = c_anchors[2*n] * is, ah = c_anchors[2*n+1] * is;
            float mw = fminf(tw, aw), mh = fminf(th, ah);
            float inter = (mw > 0.f && mh > 0.f) ? mw * mh : 0.f;
            float iou = inter / (tarea + aw * ah - inter);
            if (iou > best) { best = iou; bestn = n; }
        }
        if (valid && (bestn / 3) == group) {
            int bn = bestn % 3, gi = (int)tx, gj = (int)ty;
            selkey = (bn << 20) | (gj << 10) | gi;
        }
        clsid = (int)cf;
    }

    const int k0 = __shfl(selkey, t0);
    bool active = !(k0 & 0x40000000);                 // t0 selected?
    unsigned long long dup = __ballot(selkey == k0);
    active = active && !(dup >> (t0 + 1));            // later target wins cell

    float local = 0.f;
    if (active) {   // wave-uniform branch
        const int cls0 = __shfl(clsid, t0);
        const int gi = k0 & 1023, gj = (k0 >> 10) & 1023, bn = k0 >> 20;
        const float* base = raw + ((size_t)b * 255 + bn * 85) * HH + gj * H + gi;
        // class loss = sum_c softplus(x_c) - x_cls
        float xc = base[(size_t)(5 + lane) * HH];               // classes 0..63
        local = softplusf(xc) - ((lane == cls0) ? xc : 0.f);
        if (lane < 16) {
            float xh = base[(size_t)(69 + lane) * HH];          // classes 64..79
            local += softplusf(xh) - ((lane + 64 == cls0) ? xh : 0.f);
        }
    }
    return local;
}

__global__ __launch_bounds__(256)
void yolo_fused(const float* __restrict__ r0,
                const float* __restrict__ r1,
                const float* __restrict__ r2,
                const float* __restrict__ targets,
                float* __restrict__ partial)
{
    __shared__ SmemMain sm;
    __shared__ float s_wsum[4];

    const int blk = blockIdx.x;
    const int tid = threadIdx.x;
    float local = 0.f;

    // class blocks FIRST: their cold-HBM gathers overlap main-block compute
    if (blk < NB_CLS) {
        int u = blk * 4 + (tid >> 6);
        if (u < N_CLS_UNITS)
            local = class_unit(r0, r1, r2, targets, u, tid & 63);
    } else if (blk < NB_CLS + NB_L0 * NBATCH) {
        int q = blk - NB_CLS;
        int b = q / NB_L0, cb = q - b * NB_L0;
        local = main_cells<19, 32, 2>(r0, targets, b, cb, tid, &sm);
    } else if (blk < NB_CLS + (NB_L0 + NB_L1) * NBATCH) {
        int q = blk - NB_CLS - NB_L0 * NBATCH;
        int b = q / NB_L1, cb = q - b * NB_L1;
        local = main_cells<38, 16, 1>(r1, targets, b, cb, tid, &sm);
    } else {
        int q = blk - NB_CLS - (NB_L0 + NB_L1) * NBATCH;
        int b = q / NB_L2, cb = q - b * NB_L2;
        local = main_cells<76, 8, 0>(r2, targets, b, cb, tid, &sm);
    }

    // block reduction -> unique partial slot (no global atomics)
    for (int off = 32; off > 0; off >>= 1)
        local += __shfl_down(local, off, 64);
    const int lane = tid & 63, wv = tid >> 6;
    if (lane == 0) s_wsum[wv] = local;
    __syncthreads();
    if (tid == 0)
        partial[blk] = s_wsum[0] + s_wsum[1] + s_wsum[2] + s_wsum[3];
}

__global__ __launch_bounds__(256)
void yolo_reduce(const float4* __restrict__ partial4, float* __restrict__ out)
{
    const int tid = threadIdx.x;
    constexpr int NV = NB_TOTAL / 4;    // 510 float4s (NB_TOTAL % 4 == 0)
    float4 v = partial4[tid];           // tid < 256 < NV
    float s = v.x + v.y + v.z + v.w;
    if (tid + 256 < NV) {
        float4 u = partial4[tid + 256];
        s += u.x + u.y + u.z + u.w;
    }
    for (int off = 32; off > 0; off >>= 1)
        s += __shfl_down(s, off, 64);
    __shared__ float w[4];
    if ((tid & 63) == 0) w[tid >> 6] = s;
    __syncthreads();
    if (tid == 0) out[0] = w[0] + w[1] + w[2] + w[3];
}

extern "C" void kernel_launch(void* const* d_in, const int* in_sizes, int n_in,
                              void* d_out, int out_size, void* d_ws, size_t ws_size,
                              hipStream_t stream)
{
    const float* out0 = (const float*)d_in[0];
    const float* out1 = (const float*)d_in[1];
    const float* out2 = (const float*)d_in[2];
    const float* tgt  = (const float*)d_in[3];
    float* out = (float*)d_out;
    float* partial = (float*)d_ws;   // NB_TOTAL floats, all slots written

    yolo_fused<<<NB_TOTAL, 256, 0, stream>>>(out0, out1, out2, tgt, partial);
    yolo_reduce<<<1, 256, 0, stream>>>((const float4*)partial, out);
}